// Round 1
// baseline (912.687 us; speedup 1.0000x reference)
//
#include <hip/hip_runtime.h>

constexpr int B    = 64;
constexpr int S    = 4096;
constexpr int HID  = 4096;
constexpr int NH   = 32;
constexpr int HD   = 128;
constexpr int QS   = 4096;      // NH*HD
constexpr int QKVR = 4224;      // QS + HD (only rows actually used)
constexpr int E    = 8;
constexpr int MI   = 1408;
constexpr int SPLIT = 16;
constexpr float EPS = 1e-6f;

#define NEG_INF (-__builtin_inff())

// ---------------------------------------------------------------- K1: rmsnorm1
__global__ __launch_bounds__(256) void k_rms1(const float* __restrict__ hs,
                                              const float* __restrict__ w,
                                              float* __restrict__ h,
                                              int* __restrict__ cnt) {
  int b = blockIdx.x, t = threadIdx.x;
  const float* x = hs + (size_t)b * HID;
  float ss = 0.f;
  for (int i = t; i < HID / 4; i += 256) {
    float4 v = ((const float4*)x)[i];
    ss += v.x * v.x + v.y * v.y + v.z * v.z + v.w * v.w;
  }
  #pragma unroll
  for (int off = 32; off >= 1; off >>= 1) ss += __shfl_xor(ss, off);
  __shared__ float red[4];
  if ((t & 63) == 0) red[t >> 6] = ss;
  __syncthreads();
  float inv = rsqrtf((red[0] + red[1] + red[2] + red[3]) / HID + EPS);
  for (int i = t; i < HID / 4; i += 256) {
    float4 v = ((const float4*)x)[i];
    float4 wv = ((const float4*)w)[i];
    float4 o;
    o.x = v.x * inv * wv.x; o.y = v.y * inv * wv.y;
    o.z = v.z * inv * wv.z; o.w = v.w * inv * wv.w;
    ((float4*)(h + (size_t)b * HID))[i] = o;
  }
  if (b == 0 && t < E) cnt[t] = 0;   // zero expert counters for this call
}

// ------------------------------------------------- K2/K5: skinny GEMM, 16 rows/block
// C[s][r0+r] = sum_k A[s][k] * W[r0+r][k]   (64 slots = batch, W row stride = K)
template <int K, bool EPI_HS>
__global__ __launch_bounds__(256) void k_gemm16(const float* __restrict__ A,
                                                const float* __restrict__ W,
                                                const float* __restrict__ hsrc,
                                                float* __restrict__ C, int ldc) {
  __shared__ __align__(16) float As[64][68];  // [k][slot]
  __shared__ float Ws[64][17];                // [k][r]
  int r0 = blockIdx.x * 16;
  int t = threadIdx.x;
  int r = t & 15, sg = t >> 4;                // r:0..15  sg:0..15 (4 slots each)
  float acc[4] = {0.f, 0.f, 0.f, 0.f};
  for (int k0 = 0; k0 < K; k0 += 64) {
    __syncthreads();
    #pragma unroll
    for (int i = 0; i < 4; ++i) {             // stage A: 64 slots x 64 k
      int idx = t + i * 256;
      int s = idx >> 4, kq = idx & 15;
      float4 v = *(const float4*)(A + (size_t)s * K + k0 + kq * 4);
      As[kq*4+0][s] = v.x; As[kq*4+1][s] = v.y; As[kq*4+2][s] = v.z; As[kq*4+3][s] = v.w;
    }
    {                                          // stage W: 16 rows x 64 k
      int rr = t >> 4, kq = t & 15;
      float4 v = *(const float4*)(W + (size_t)(r0 + rr) * K + k0 + kq * 4);
      Ws[kq*4+0][rr] = v.x; Ws[kq*4+1][rr] = v.y; Ws[kq*4+2][rr] = v.z; Ws[kq*4+3][rr] = v.w;
    }
    __syncthreads();
    #pragma unroll
    for (int k = 0; k < 64; ++k) {
      float wv = Ws[k][r];
      float4 av = *(const float4*)(&As[k][sg * 4]);
      acc[0] += av.x * wv; acc[1] += av.y * wv;
      acc[2] += av.z * wv; acc[3] += av.w * wv;
    }
  }
  #pragma unroll
  for (int j = 0; j < 4; ++j) {
    int s = sg * 4 + j;
    float o = acc[j];
    if (EPI_HS) o += hsrc[(size_t)s * HID + r0 + r];
    C[(size_t)s * ldc + r0 + r] = o;
  }
}

// ---------------------------------------------------------------- K3: flash-decode
__global__ __launch_bounds__(256) void k_attn(const float* __restrict__ kcache,
                                              const float* __restrict__ vcache,
                                              const float* __restrict__ qkv,
                                              const int* __restrict__ seq_lens,
                                              float* __restrict__ ctxp,
                                              float* __restrict__ mpart,
                                              float* __restrict__ lpart) {
  int sp = blockIdx.x, b = blockIdx.y;
  int L = seq_lens[b];
  int chunk = (L + SPLIT - 1) / SPLIT;
  int s_beg = sp * chunk;
  int s_end = min(L, s_beg + chunk);
  int t = threadIdx.x;
  int wv = t >> 6, lane = t & 63;
  int sidx = lane & 31, dh = lane >> 5;

  __shared__ float qlds[NH * HD];     // 16 KB
  __shared__ float klds[32][129];     // stride 129: (s+d)%32 -> conflict-free
  __shared__ float vlds[32][129];

  for (int i = t; i < NH * HD / 4; i += 256)
    ((float4*)qlds)[i] = ((const float4*)(qkv + (size_t)b * QKVR))[i];

  float m[8], ls[8], c0[8], c1[8];
  #pragma unroll
  for (int j = 0; j < 8; ++j) { m[j] = NEG_INF; ls[j] = 0.f; c0[j] = 0.f; c1[j] = 0.f; }

  const float scale = 0.0883883476483184f;   // 1/sqrt(128)

  for (int s0 = s_beg; s0 < s_end; s0 += 32) {
    int ns = min(32, s_end - s0);
    __syncthreads();
    #pragma unroll
    for (int i = 0; i < 4; ++i) {            // stage 32 k-rows + v-rows
      int idx = t + i * 256;
      int row = idx >> 5, q4 = idx & 31;
      if (row < ns) {
        int s = s0 + row;
        bool cur = (s == L - 1);             // cache update: kcur into BOTH k and v
        const float* ksrc = cur ? (qkv + (size_t)b * QKVR + QS)
                                : (kcache + ((size_t)b * S + s) * HD);
        const float* vsrc = cur ? ksrc : (vcache + ((size_t)b * S + s) * HD);
        float4 kv = *(const float4*)(ksrc + q4 * 4);
        float4 vv = *(const float4*)(vsrc + q4 * 4);
        klds[row][q4*4+0] = kv.x; klds[row][q4*4+1] = kv.y;
        klds[row][q4*4+2] = kv.z; klds[row][q4*4+3] = kv.w;
        vlds[row][q4*4+0] = vv.x; vlds[row][q4*4+1] = vv.y;
        vlds[row][q4*4+2] = vv.z; vlds[row][q4*4+3] = vv.w;
      }
    }
    __syncthreads();
    #pragma unroll
    for (int j = 0; j < 8; ++j) {
      int h = wv * 8 + j;
      float sc = 0.f;
      if (sidx < ns) {
        const float* qp = qlds + h * HD + dh * 64;
        #pragma unroll
        for (int i = 0; i < 64; ++i) sc += qp[i] * klds[sidx][dh * 64 + i];
      }
      sc += __shfl_xor(sc, 32);             // combine the two d-halves
      sc *= scale;
      if (sidx >= ns) sc = NEG_INF;
      float tm = sc;
      #pragma unroll
      for (int off = 16; off >= 1; off >>= 1) tm = fmaxf(tm, __shfl_xor(tm, off));
      float mnew = fmaxf(m[j], tm);
      float alpha = __expf(m[j] - mnew);
      float p = (sidx < ns) ? __expf(sc - mnew) : 0.f;
      float ps = p;
      #pragma unroll
      for (int off = 16; off >= 1; off >>= 1) ps += __shfl_xor(ps, off);
      ls[j] = ls[j] * alpha + ps;
      m[j] = mnew;
      c0[j] *= alpha; c1[j] *= alpha;
      for (int s = 0; s < ns; ++s) {        // PV: lane <-> d
        float pb = __shfl(p, s);
        c0[j] += pb * vlds[s][lane];
        c1[j] += pb * vlds[s][lane + 64];
      }
    }
  }
  #pragma unroll
  for (int j = 0; j < 8; ++j) {
    int h = wv * 8 + j;
    size_t pb = ((size_t)b * SPLIT + sp) * NH + h;
    ctxp[pb * HD + lane]      = c0[j];
    ctxp[pb * HD + lane + 64] = c1[j];
    if (lane == 0) { mpart[pb] = m[j]; lpart[pb] = ls[j]; }
  }
}

// ---------------------------------------------------------------- K4: split combine
__global__ void k_comb(const float* __restrict__ ctxp, const float* __restrict__ mpart,
                       const float* __restrict__ lpart, float* __restrict__ ctx) {
  int bh = blockIdx.x;
  int b = bh >> 5, h = bh & 31;
  int d = threadIdx.x;                       // 128 threads
  float M = NEG_INF;
  #pragma unroll
  for (int sp = 0; sp < SPLIT; ++sp)
    M = fmaxf(M, mpart[((size_t)b * SPLIT + sp) * NH + h]);
  float acc = 0.f, L = 0.f;
  #pragma unroll
  for (int sp = 0; sp < SPLIT; ++sp) {
    size_t pb = ((size_t)b * SPLIT + sp) * NH + h;
    float w = __expf(mpart[pb] - M);         // empty split: exp(-inf)=0
    acc += w * ctxp[pb * HD + d];
    L   += w * lpart[pb];
  }
  ctx[(size_t)b * QS + h * HD + d] = acc / L;
}

// ---------------------------------------------------------------- K6: rmsnorm2 + gate + route
__global__ __launch_bounds__(256) void k_rms2gate(const float* __restrict__ hidden,
                                                  const float* __restrict__ w,
                                                  const float* __restrict__ gw,
                                                  float* __restrict__ x2,
                                                  int* __restrict__ cnt,
                                                  int* __restrict__ etok,
                                                  float* __restrict__ ewt) {
  int b = blockIdx.x, t = threadIdx.x;
  __shared__ float xs[HID];
  __shared__ float red[4];
  __shared__ float logits[E];
  const float* hb = hidden + (size_t)b * HID;
  float ss = 0.f;
  for (int i = t; i < HID / 4; i += 256) {
    float4 v = ((const float4*)hb)[i];
    ss += v.x * v.x + v.y * v.y + v.z * v.z + v.w * v.w;
  }
  #pragma unroll
  for (int off = 32; off >= 1; off >>= 1) ss += __shfl_xor(ss, off);
  if ((t & 63) == 0) red[t >> 6] = ss;
  __syncthreads();
  float inv = rsqrtf((red[0] + red[1] + red[2] + red[3]) / HID + EPS);
  for (int i = t; i < HID / 4; i += 256) {
    float4 v = ((const float4*)hb)[i];
    float4 wv = ((const float4*)w)[i];
    float4 o;
    o.x = v.x * inv * wv.x; o.y = v.y * inv * wv.y;
    o.z = v.z * inv * wv.z; o.w = v.w * inv * wv.w;
    ((float4*)(x2 + (size_t)b * HID))[i] = o;
    ((float4*)xs)[i] = o;
  }
  __syncthreads();
  int e = t >> 5, ln = t & 31;
  float acc = 0.f;
  for (int k = ln; k < HID; k += 32) acc += xs[k] * gw[(size_t)e * HID + k];
  #pragma unroll
  for (int off = 16; off >= 1; off >>= 1) acc += __shfl_xor(acc, off);
  if (ln == 0) logits[e] = acc;
  __syncthreads();
  if (t == 0) {
    float mx = logits[0];
    #pragma unroll
    for (int i = 1; i < E; ++i) mx = fmaxf(mx, logits[i]);
    float pr[E];
    #pragma unroll
    for (int i = 0; i < E; ++i) pr[i] = __expf(logits[i] - mx);
    int i0 = 0;
    #pragma unroll
    for (int i = 1; i < E; ++i) if (pr[i] > pr[i0]) i0 = i;
    int i1 = (i0 == 0) ? 1 : 0;
    #pragma unroll
    for (int i = 0; i < E; ++i) if (i != i0 && pr[i] > pr[i1]) i1 = i;
    float sw = pr[i0] + pr[i1];
    float w0 = pr[i0] / sw, w1 = pr[i1] / sw;
    int s0 = atomicAdd(&cnt[i0], 1); etok[i0 * B + s0] = b; ewt[i0 * B + s0] = w0;
    int s1 = atomicAdd(&cnt[i1], 1); etok[i1 * B + s1] = b; ewt[i1 * B + s1] = w1;
  }
}

// ---------------------------------------------------------------- K7a: gu = x2 @ w1[e]^T
__global__ __launch_bounds__(256) void k_moe1(const float* __restrict__ x2,
                                              const float* __restrict__ w1,
                                              const int* __restrict__ cnt,
                                              const int* __restrict__ etok,
                                              float* __restrict__ gu) {
  int e = blockIdx.y;
  int n = cnt[e];
  if (n == 0) return;
  int nsc = (n + 31) >> 5;                   // 1 or 2 slot-chunks of 32
  int SP = nsc * 32;
  int r0 = blockIdx.x * 32;
  int t = threadIdx.x;
  int r = t & 31, sg = t >> 5;
  __shared__ __align__(16) float As[64][68];
  __shared__ float Ws[64][33];
  float acc[2][4] = {};
  const float* Wb = w1 + (size_t)e * 2816 * HID + (size_t)r0 * HID;
  for (int k0 = 0; k0 < HID; k0 += 64) {
    __syncthreads();
    for (int idx = t; idx < SP * 16; idx += 256) {   // gather-stage A
      int s = idx >> 4, kq = idx & 15;
      float4 v = make_float4(0.f, 0.f, 0.f, 0.f);
      if (s < n) {
        int tok = etok[e * B + s];
        v = *(const float4*)(x2 + (size_t)tok * HID + k0 + kq * 4);
      }
      As[kq*4+0][s] = v.x; As[kq*4+1][s] = v.y; As[kq*4+2][s] = v.z; As[kq*4+3][s] = v.w;
    }
    #pragma unroll
    for (int i = 0; i < 2; ++i) {                    // stage W: 32 rows x 64 k
      int idx = t + i * 256;
      int rr = idx >> 4, kq = idx & 15;
      float4 v = *(const float4*)(Wb + (size_t)rr * HID + k0 + kq * 4);
      Ws[kq*4+0][rr] = v.x; Ws[kq*4+1][rr] = v.y; Ws[kq*4+2][rr] = v.z; Ws[kq*4+3][rr] = v.w;
    }
    __syncthreads();
    if (nsc == 1) {
      #pragma unroll
      for (int k = 0; k < 64; ++k) {
        float wv = Ws[k][r];
        float4 a0 = *(const float4*)(&As[k][sg * 4]);
        acc[0][0] += a0.x * wv; acc[0][1] += a0.y * wv;
        acc[0][2] += a0.z * wv; acc[0][3] += a0.w * wv;
      }
    } else {
      #pragma unroll
      for (int k = 0; k < 64; ++k) {
        float wv = Ws[k][r];
        float4 a0 = *(const float4*)(&As[k][sg * 4]);
        float4 a1 = *(const float4*)(&As[k][32 + sg * 4]);
        acc[0][0] += a0.x * wv; acc[0][1] += a0.y * wv;
        acc[0][2] += a0.z * wv; acc[0][3] += a0.w * wv;
        acc[1][0] += a1.x * wv; acc[1][1] += a1.y * wv;
        acc[1][2] += a1.z * wv; acc[1][3] += a1.w * wv;
      }
    }
  }
  #pragma unroll
  for (int sc = 0; sc < 2; ++sc)
    if (sc < nsc)
      #pragma unroll
      for (int j = 0; j < 4; ++j) {
        int s = sc * 32 + sg * 4 + j;
        if (s < n) gu[((size_t)e * B + s) * 2816 + r0 + r] = acc[sc][j];
      }
}

// ---------------------------------------------------------------- K7b: silu(g)*u
__global__ void k_silu(const float* __restrict__ gu, const int* __restrict__ cnt,
                       float* __restrict__ mid) {
  int e = blockIdx.y, s = blockIdx.x;
  if (s >= cnt[e]) return;
  const float* row = gu + ((size_t)e * B + s) * 2816;
  float* o = mid + ((size_t)e * B + s) * MI;
  for (int i = threadIdx.x; i < MI; i += 256) {
    float g = row[i], u = row[MI + i];
    o[i] = g / (1.f + __expf(-g)) * u;
  }
}

// ---------------------------------------------------------------- K7c: out += wt * (mid @ w2[e]^T)
__global__ __launch_bounds__(256) void k_moe2(const float* __restrict__ mid,
                                              const float* __restrict__ w2,
                                              const int* __restrict__ cnt,
                                              const int* __restrict__ etok,
                                              const float* __restrict__ ewt,
                                              float* __restrict__ out) {
  int e = blockIdx.y;
  int n = cnt[e];
  if (n == 0) return;
  int nsc = (n + 31) >> 5;
  int SP = nsc * 32;
  int r0 = blockIdx.x * 32;
  int t = threadIdx.x;
  int r = t & 31, sg = t >> 5;
  __shared__ __align__(16) float As[64][68];
  __shared__ float Ws[64][33];
  float acc[2][4] = {};
  const float* Wb = w2 + (size_t)e * HID * MI + (size_t)r0 * MI;
  for (int k0 = 0; k0 < MI; k0 += 64) {
    __syncthreads();
    for (int idx = t; idx < SP * 16; idx += 256) {
      int s = idx >> 4, kq = idx & 15;
      float4 v = make_float4(0.f, 0.f, 0.f, 0.f);
      if (s < n) v = *(const float4*)(mid + ((size_t)e * B + s) * MI + k0 + kq * 4);
      As[kq*4+0][s] = v.x; As[kq*4+1][s] = v.y; As[kq*4+2][s] = v.z; As[kq*4+3][s] = v.w;
    }
    #pragma unroll
    for (int i = 0; i < 2; ++i) {
      int idx = t + i * 256;
      int rr = idx >> 4, kq = idx & 15;
      float4 v = *(const float4*)(Wb + (size_t)rr * MI + k0 + kq * 4);
      Ws[kq*4+0][rr] = v.x; Ws[kq*4+1][rr] = v.y; Ws[kq*4+2][rr] = v.z; Ws[kq*4+3][rr] = v.w;
    }
    __syncthreads();
    if (nsc == 1) {
      #pragma unroll
      for (int k = 0; k < 64; ++k) {
        float wv = Ws[k][r];
        float4 a0 = *(const float4*)(&As[k][sg * 4]);
        acc[0][0] += a0.x * wv; acc[0][1] += a0.y * wv;
        acc[0][2] += a0.z * wv; acc[0][3] += a0.w * wv;
      }
    } else {
      #pragma unroll
      for (int k = 0; k < 64; ++k) {
        float wv = Ws[k][r];
        float4 a0 = *(const float4*)(&As[k][sg * 4]);
        float4 a1 = *(const float4*)(&As[k][32 + sg * 4]);
        acc[0][0] += a0.x * wv; acc[0][1] += a0.y * wv;
        acc[0][2] += a0.z * wv; acc[0][3] += a0.w * wv;
        acc[1][0] += a1.x * wv; acc[1][1] += a1.y * wv;
        acc[1][2] += a1.z * wv; acc[1][3] += a1.w * wv;
      }
    }
  }
  #pragma unroll
  for (int sc = 0; sc < 2; ++sc)
    if (sc < nsc)
      #pragma unroll
      for (int j = 0; j < 4; ++j) {
        int s = sc * 32 + sg * 4 + j;
        if (s < n) {
          int tok = etok[e * B + s];
          atomicAdd(&out[(size_t)tok * HID + r0 + r], ewt[e * B + s] * acc[sc][j]);
        }
      }
}

// ================================================================ launch
extern "C" void kernel_launch(void* const* d_in, const int* in_sizes, int n_in,
                              void* d_out, int out_size, void* d_ws, size_t ws_size,
                              hipStream_t stream) {
  const float* hs   = (const float*)d_in[0];
  // d_in[1] = positions: unused by the reference
  const float* kcache = (const float*)d_in[2];
  const float* vcache = (const float*)d_in[3];
  const int*   seq  = (const int*)d_in[4];
  const float* n1w  = (const float*)d_in[5];
  const float* n2w  = (const float*)d_in[6];
  const float* wqkv = (const float*)d_in[7];
  const float* wo   = (const float*)d_in[8];
  const float* gw   = (const float*)d_in[9];
  const float* w1   = (const float*)d_in[10];
  const float* w2   = (const float*)d_in[11];
  float* out = (float*)d_out;
  float* ws  = (float*)d_ws;

  float* h     = ws;                       // 262144
  float* qkvb  = h + 262144;               // 64*4224 = 270336
  float* ctxp  = qkvb + 270336;            // 64*16*32*128 = 4194304 (reused by gu/mid)
  float* mpart = ctxp + 4194304;           // 32768
  float* lpart = mpart + 32768;            // 32768
  float* ctx   = lpart + 32768;            // 262144
  float* x2    = ctx + 262144;             // 262144
  float* ewt   = x2 + 262144;              // 512
  int*   cnt   = (int*)(ewt + 512);        // 8
  int*   etok  = cnt + 8;                  // 512
  float* gu    = ctxp;                     // alias: 8*64*2816 = 1441792 (ctxp dead after K4)
  float* mid   = ctxp + 1441792;           // 8*64*1408 = 720896

  k_rms1<<<B, 256, 0, stream>>>(hs, n1w, h, cnt);
  k_gemm16<HID, false><<<QKVR / 16, 256, 0, stream>>>(h, wqkv, nullptr, qkvb, QKVR);
  k_attn<<<dim3(SPLIT, B), 256, 0, stream>>>(kcache, vcache, qkvb, seq, ctxp, mpart, lpart);
  k_comb<<<B * NH, HD, 0, stream>>>(ctxp, mpart, lpart, ctx);
  k_gemm16<HID, true><<<HID / 16, 256, 0, stream>>>(ctx, wo, hs, out, HID);
  k_rms2gate<<<B, 256, 0, stream>>>(out, n2w, gw, x2, cnt, etok, ewt);
  k_moe1<<<dim3(2816 / 32, E), 256, 0, stream>>>(x2, w1, cnt, etok, gu);
  k_silu<<<dim3(B, E), 256, 0, stream>>>(gu, cnt, mid);
  k_moe2<<<dim3(HID / 32, E), 256, 0, stream>>>(mid, w2, cnt, etok, ewt, out);
}